// Round 16
// baseline (231.678 us; speedup 1.0000x reference)
//
#include <hip/hip_runtime.h>
#include <hip/hip_bf16.h>

#define NB 8
#define NN 4096
#define NM 4096
#define NC 128
#define NK 16
#define CINP 160   // cin padded for layer 0 (5 K-tiles of 32)
#define NGQ 4      // queries per group
#define NPT 64     // points per group (NGQ*16)
#define NG 32      // groups per block (128 queries / block)

typedef __attribute__((ext_vector_type(8))) short short8;
typedef __attribute__((ext_vector_type(4))) short short4v;
typedef __attribute__((ext_vector_type(4))) float f32x4;

__device__ __forceinline__ short f2bf(float f) {
    __hip_bfloat16 h = __float2bfloat16(f);
    return (short)__builtin_bit_cast(unsigned short, h);
}

// ---------------------------------------------------------------------------
// Kernel A: weight transpose + bf16 convert.  W0[131][128] -> w0t[128][160]
// ---------------------------------------------------------------------------
__global__ void convert_w_kernel(const float* __restrict__ W0, const float* __restrict__ W1,
                                 const float* __restrict__ W2, ushort* __restrict__ w0t,
                                 ushort* __restrict__ w1t, ushort* __restrict__ w2t) {
    int bx = blockIdx.x;            // 0..383
    int mat = bx >> 7;
    int cout = bx & 127;
    int k = threadIdx.x;            // 0..159
    if (mat == 0) {
        float v = (k < 131) ? W0[k * NC + cout] : 0.0f;
        w0t[cout * CINP + k] = (ushort)f2bf(v);
    } else if (k < 128) {
        const float* W = (mat == 1) ? W1 : W2;
        ushort* wt = (mat == 1) ? w1t : w2t;
        wt[cout * NC + k] = (ushort)f2bf(W[k * NC + cout]);
    }
}

// ---------------------------------------------------------------------------
// Kernel 0: copy xyz1 -> d_out; pack xyz2 -> (x,y,z,|b|^2) float4
//           (+ zero the fallback counter — runs before knn on the stream)
// ---------------------------------------------------------------------------
__global__ void copy_xyz_kernel(const float* __restrict__ src, float* __restrict__ dst) {
    int i = blockIdx.x * blockDim.x + threadIdx.x;   // 24576 float4s exactly
    ((float4*)dst)[i] = ((const float4*)src)[i];
}

__global__ void pack_xyz2_kernel(const float* __restrict__ xyz2, float4* __restrict__ packed,
                                 int* __restrict__ fb_count) {
    int i = blockIdx.x * blockDim.x + threadIdx.x;   // B*M total
    if (i == 0) *fb_count = 0;
    const float* p = xyz2 + 3 * (size_t)i;
    float x = p[0], y = p[1], z = p[2];
    packed[i] = make_float4(x, y, z, x * x + y * y + z * z);
}

// ---------------------------------------------------------------------------
// Kernel 1: KNN — R21: R17's proven-best frame (LDS-staged batch, ONE query
//   per wave, (512,4)) with its one measured defect excised: the sv[64]
//   stash was scratch-demoted (R17 VGPR=60 -> 64 scratch stores + 64 loads
//   per query).  Phase B now RECOMPUTES from the still-resident LDS tile
//   (R18-verified: identical fmaf sequence -> bit-identical s -> identical
//   selection), and the rare exact fallback is deferred to the cleanup
//   kernel (R20-verified) so the main kernel carries ZERO scratch.
// ---------------------------------------------------------------------------
__device__ __forceinline__ unsigned f2ord(float f) {
    unsigned u = __builtin_bit_cast(unsigned, f);
    return (u & 0x80000000u) ? ~u : (u | 0x80000000u);
}
__device__ __forceinline__ float ord2f(unsigned u) {
    unsigned b = (u & 0x80000000u) ? (u & 0x7fffffffu) : ~u;
    return __builtin_bit_cast(float, b);
}

template<int KC>
__device__ __forceinline__ void scan_lane(const float4* __restrict__ x2p, int lane,
                                          float ax, float ay, float az,
                                          float* bd, int* bi) {
#pragma unroll
    for (int j = 0; j < KC; j++) { bd[j] = 3.4e38f; bi[j] = -1; }
#pragma unroll 2
    for (int i = 0; i < 64; i++) {
        int m = (i << 6) | lane;
        float4 f = x2p[m];
        float v = fmaf(f.x, ax, fmaf(f.y, ay, fmaf(f.z, az, f.w)));
        int vi = m;
#pragma unroll
        for (int j = 0; j < KC; j++) {
            bool c = v < bd[j];
            float nd = c ? v : bd[j];
            float cv = c ? bd[j] : v;
            int ni = c ? vi : bi[j];
            int ci = c ? bi[j] : vi;
            bd[j] = nd; bi[j] = ni; v = cv; vi = ci;
        }
    }
}

template<int KC>
__device__ __forceinline__ float extract16(float* bd, int* bi, int lane, int& outm) {
    float lastd = 0.0f;
    for (int r = 0; r < 16; r++) {
        float md = bd[0]; int mm = bi[0];
#pragma unroll
        for (int s = 1; s < 64; s <<= 1) {
            float od = __shfl_xor(md, s);
            int om = __shfl_xor(mm, s);
            bool t = (od < md) || (od == md && om < mm);
            md = t ? od : md;
            mm = t ? om : mm;
        }
        if (bd[0] == md && bi[0] == mm) {
#pragma unroll
            for (int j = 0; j < KC - 1; j++) { bd[j] = bd[j + 1]; bi[j] = bi[j + 1]; }
            bd[KC - 1] = 3.4e38f; bi[KC - 1] = -1;
        }
        if (lane == r) outm = mm;
        lastd = md;
    }
    return lastd;
}

__global__ __launch_bounds__(512, 4) void knn_kernel(const float* __restrict__ xyz1,
                                                     const float4* __restrict__ xyz2p,
                                                     int* __restrict__ out_idx,
                                                     int* __restrict__ fb_count,
                                                     int* __restrict__ fb_list) {
    __shared__ __align__(16) float4 smem[NM];   // 64 KB: batch slice of packed xyz2

    int tid = threadIdx.x;
    int lane = tid & 63;
    int w = tid >> 6;
    int Q = blockIdx.x * 8 + w;
    int b = Q >> 12;                 // all 8 waves of a block share one batch
    const float4* x2g = xyz2p + ((size_t)b << 12);

    // cooperative stage: 64 KB, 8 float4 per thread, conflict-free stride
#pragma unroll
    for (int j = 0; j < NM / 512; j++) smem[j * 512 + tid] = x2g[j * 512 + tid];

    const float* qp = xyz1 + (size_t)Q * 3;
    float ax = -2.0f * qp[0], ay = -2.0f * qp[1], az = -2.0f * qp[2];
    __syncthreads();

    // ---- Phase A: LDS reads + keys-only top-4 merge network (no stash) ----
    float t0 = 3.4e38f, t1 = 3.4e38f, t2 = 3.4e38f, t3 = 3.4e38f;
#pragma unroll 4
    for (int i = 0; i < 64; i += 2) {
        float4 f = smem[(i << 6) | lane];
        float4 g = smem[((i + 1) << 6) | lane];
        float s0 = fmaf(f.x, ax, fmaf(f.y, ay, fmaf(f.z, az, f.w)));
        float s1 = fmaf(g.x, ax, fmaf(g.y, ay, fmaf(g.z, az, g.w)));
        float v0 = fminf(s0, s1), v1 = fmaxf(s0, s1);
        t3 = fminf(fminf(t3, fmaxf(t2, v0)), fmaxf(t1, v1));
        t2 = fminf(fminf(t2, fmaxf(t1, v0)), fmaxf(t0, v1));
        t1 = fminf(fminf(fmaxf(t0, v0), t1), v1);
        t0 = fminf(t0, v0);
    }

    // ---- Extract exact 16th-smallest via ordinal binary search ----
    unsigned k0 = f2ord(t0), k1 = f2ord(t1), k2 = f2ord(t2), k3 = f2ord(t3);
    unsigned lo = 0u, hi = 0xffffffffu;
    for (int it = 0; it < 32; ++it) {
        unsigned mid = lo + ((hi - lo) >> 1);
        int c = __popcll(__ballot(k0 <= mid)) + __popcll(__ballot(k1 <= mid))
              + __popcll(__ballot(k2 <= mid)) + __popcll(__ballot(k3 <= mid));
        if (c >= 16) hi = mid; else lo = mid + 1;
    }
    float thr = ord2f(hi);           // exact 16th-smallest key (ties included)

    if (__any(k3 <= hi)) {
        // rare (P ~ 0.7%/query): defer exact payload pass to cleanup kernel
        if (lane == 0) {
            int slot = atomicAdd(fb_count, 1);
            fb_list[slot] = Q;
        }
    } else {
        // ---- Phase B: LDS re-read + recompute + ordered emission ----
        int base = 0;
#pragma unroll 2
        for (int i = 0; i < 64; ++i) {
            float4 f = smem[(i << 6) | lane];
            float s = fmaf(f.x, ax, fmaf(f.y, ay, fmaf(f.z, az, f.w)));
            bool hit = s <= thr;
            unsigned long long mask = __ballot(hit);
            if (mask) {                    // wave-uniform skip (~70% of iters)
                int pos = base + __popcll(mask & ((1ull << lane) - 1));
                if (hit && pos < NK)
                    out_idx[(size_t)Q * NK + pos] = (i << 6) | lane;
                base += __popcll(mask);
            }
        }
    }
}

// ---------------------------------------------------------------------------
// Kernel 1b: exact cleanup for flagged queries (scratch lives HERE only).
//   ~230 expected flagged queries; one wave each; grid-stride over the list.
// ---------------------------------------------------------------------------
__global__ __launch_bounds__(512, 1) void knn_fix_kernel(const float* __restrict__ xyz1,
                                                         const float4* __restrict__ xyz2p,
                                                         const int* __restrict__ fb_count,
                                                         const int* __restrict__ fb_list,
                                                         int* __restrict__ out_idx) {
    int lane = threadIdx.x & 63;
    int wid = (blockIdx.x * blockDim.x + threadIdx.x) >> 6;
    int nw = (gridDim.x * blockDim.x) >> 6;
    int cnt = *fb_count;
    for (int i = wid; i < cnt; i += nw) {
        int Q = fb_list[i];
        int b = Q >> 12;
        const float4* x2g = xyz2p + ((size_t)b << 12);
        const float* qp = xyz1 + (size_t)Q * 3;
        float ax = -2.0f * qp[0], ay = -2.0f * qp[1], az = -2.0f * qp[2];
        float bd[16]; int bi[16];
        scan_lane<16>(x2g, lane, ax, ay, az, bd, bi);
        int outm = -1;
        extract16<16>(bd, bi, lane, outm);
        if (lane < NK) out_idx[(size_t)Q * NK + lane] = outm;
    }
}

// ---------------------------------------------------------------------------
// Kernel 2: fused gather + corr + 3-layer MLP (bf16 MFMA) + maxpool.
// R21 = R17 mlp verbatim (verified best: hybrid orientation — swapped L0/L1
//   with b64 LDS stores, non-swapped L2 with cheap maxpool — 2 barriers).
// ---------------------------------------------------------------------------
struct Stage {
    float4 r[8];          // r[0..3] = feat2 slice, r[4..7] = feat1 slice
    float dx, dy, dz;     // xyz diff (tid < NPT only)
};

__device__ __forceinline__ void gather_load(Stage& st,
    const float* __restrict__ xyz1, const float* __restrict__ feat1,
    const float* __restrict__ xyz2, const float* __restrict__ feat2,
    const int* __restrict__ knn, size_t bn, int qbase, int tid) {
    int pt = tid >> 3, oct = tid & 7;              // pt 0..63 with 512 threads
    int n = qbase + (pt >> 4);
    int m = knn[(bn + n) * NK + (pt & 15)];
    const float* f2 = feat2 + (bn + m) * NC + oct * 16;
    const float* f1 = feat1 + (bn + n) * NC + oct * 16;
#pragma unroll
    for (int i = 0; i < 4; i++) st.r[i] = ((const float4*)f2)[i];
#pragma unroll
    for (int i = 0; i < 4; i++) st.r[4 + i] = ((const float4*)f1)[i];
    if (tid < NPT) {
        int pt2 = tid;
        int n2 = qbase + (pt2 >> 4);
        int m2 = knn[(bn + n2) * NK + (pt2 & 15)];
        const float* p2 = xyz2 + (bn + m2) * 3;
        const float* p1 = xyz1 + (bn + n2) * 3;
        st.dx = p2[0] - p1[0];
        st.dy = p2[1] - p1[1];
        st.dz = p2[2] - p1[2];
    }
}

__device__ __forceinline__ void gather_store(const Stage& st, char* __restrict__ buf, int tid) {
    int pt = tid >> 3, oct = tid & 7;
    short8 c0, c1;
    c0[0] = f2bf(st.r[0].x * st.r[4].x); c0[1] = f2bf(st.r[0].y * st.r[4].y);
    c0[2] = f2bf(st.r[0].z * st.r[4].z); c0[3] = f2bf(st.r[0].w * st.r[4].w);
    c0[4] = f2bf(st.r[1].x * st.r[5].x); c0[5] = f2bf(st.r[1].y * st.r[5].y);
    c0[6] = f2bf(st.r[1].z * st.r[5].z); c0[7] = f2bf(st.r[1].w * st.r[5].w);
    c1[0] = f2bf(st.r[2].x * st.r[6].x); c1[1] = f2bf(st.r[2].y * st.r[6].y);
    c1[2] = f2bf(st.r[2].z * st.r[6].z); c1[3] = f2bf(st.r[2].w * st.r[6].w);
    c1[4] = f2bf(st.r[3].x * st.r[7].x); c1[5] = f2bf(st.r[3].y * st.r[7].y);
    c1[6] = f2bf(st.r[3].z * st.r[7].z); c1[7] = f2bf(st.r[3].w * st.r[7].w);
    int base = pt * (CINP * 2) + oct * 32;
    int sw = (pt & 7) << 4;
    *(short8*)(buf + (base ^ sw)) = c0;
    *(short8*)(buf + ((base + 16) ^ sw)) = c1;
    if (tid < NPT) {
        int pt2 = tid;
        short8 cz = {0, 0, 0, 0, 0, 0, 0, 0};
        short8 cx = cz;
        cx[0] = f2bf(st.dx); cx[1] = f2bf(st.dy); cx[2] = f2bf(st.dz);
        int base2 = pt2 * (CINP * 2) + 256;
        int sw2 = (pt2 & 7) << 4;
        *(short8*)(buf + (base2 ^ sw2)) = cx;
        *(short8*)(buf + ((base2 + 16) ^ sw2)) = cz;
        *(short8*)(buf + ((base2 + 32) ^ sw2)) = cz;
        *(short8*)(buf + ((base2 + 48) ^ sw2)) = cz;
    }
}

// stage a [rows][COLS] bf16 weight matrix into LDS with the row-XOR swizzle
template<int COLS>
__device__ __forceinline__ void stage_w(char* __restrict__ dst, const ushort* __restrict__ src,
                                        int rows, int tid, int nthreads) {
    const int CPR = COLS / 8;            // short8 chunks per row
    int chunks = rows * CPR;
    for (int c = tid; c < chunks; c += nthreads) {
        int row = c / CPR;
        int col8 = c % CPR;
        short8 v = *(const short8*)(src + c * 8);
        int byte = row * (COLS * 2) + col8 * 16;
        *(short8*)(dst + (byte ^ ((row & 7) << 4))) = v;
    }
}

// L0 (swapped operands): LDS weights as A, activations as B.  [verified R11/R13]
__device__ __forceinline__ void layer0_sw(const char* __restrict__ in, const char* __restrict__ wl,
                                          const float* __restrict__ bl, f32x4 acc[2][2],
                                          int arow0, int asw, int kseg, int coutw, int cout0) {
    short8 af[2][5];
#pragma unroll
    for (int rt = 0; rt < 2; rt++)
#pragma unroll
        for (int kt = 0; kt < 5; kt++) {
            int byte = (arow0 + rt * 16) * (CINP * 2) + (kt * 32 + kseg) * 2;
            af[rt][kt] = *(const short8*)(in + (byte ^ asw));
        }
#pragma unroll
    for (int jt = 0; jt < 2; jt++) {
        float4 bb = *(const float4*)(bl + cout0 + jt * 16);
#pragma unroll
        for (int rt = 0; rt < 2; rt++)
            acc[rt][jt] = (f32x4){bb.x, bb.y, bb.z, bb.w};
        int wbase = (coutw + jt * 16) * (CINP * 2) + kseg * 2;
#pragma unroll
        for (int kt = 0; kt < 5; kt++) {
            short8 wf = *(const short8*)(wl + ((wbase + kt * 64) ^ asw));
#pragma unroll
            for (int rt = 0; rt < 2; rt++)
                acc[rt][jt] = __builtin_amdgcn_mfma_f32_16x16x32_bf16(wf, af[rt][kt],
                                                                     acc[rt][jt], 0, 0, 0);
        }
    }
}

// L1 (swapped): register weight frags as A (wf[jt*4+kt], const-indexed)
__device__ __forceinline__ void layer_rw_sw(const char* __restrict__ in, const short8* __restrict__ wf,
                                            const float* __restrict__ bl, f32x4 acc[2][2],
                                            int arow0, int asw, int kseg, int cout0) {
    short8 af[2][4];
#pragma unroll
    for (int rt = 0; rt < 2; rt++)
#pragma unroll
        for (int kt = 0; kt < 4; kt++) {
            int byte = (arow0 + rt * 16) * (NC * 2) + (kt * 32 + kseg) * 2;
            af[rt][kt] = *(const short8*)(in + (byte ^ asw));
        }
#pragma unroll
    for (int jt = 0; jt < 2; jt++) {
        float4 bb = *(const float4*)(bl + cout0 + jt * 16);
#pragma unroll
        for (int rt = 0; rt < 2; rt++)
            acc[rt][jt] = (f32x4){bb.x, bb.y, bb.z, bb.w};
#pragma unroll
        for (int kt = 0; kt < 4; kt++)
#pragma unroll
            for (int rt = 0; rt < 2; rt++)
                acc[rt][jt] = __builtin_amdgcn_mfma_f32_16x16x32_bf16(wf[jt * 4 + kt], af[rt][kt],
                                                                     acc[rt][jt], 0, 0, 0);
    }
}

// L2 (NON-swapped, R10-verified): activations as A, register weight frags as B.
// acc holds [cout = lane&15 col][pt = (lane>>4)*4+r row] -> maxpool-friendly.
__device__ __forceinline__ void layer_rw_ns(const char* __restrict__ in, const short8* __restrict__ wf,
                                            const float bb[2], f32x4 acc[2][2],
                                            int arow0, int asw, int kseg) {
    short8 af[2][4];
#pragma unroll
    for (int rt = 0; rt < 2; rt++)
#pragma unroll
        for (int kt = 0; kt < 4; kt++) {
            int byte = (arow0 + rt * 16) * (NC * 2) + (kt * 32 + kseg) * 2;
            af[rt][kt] = *(const short8*)(in + (byte ^ asw));
        }
#pragma unroll
    for (int jt = 0; jt < 2; jt++) {
#pragma unroll
        for (int rt = 0; rt < 2; rt++)
            acc[rt][jt] = (f32x4){bb[jt], bb[jt], bb[jt], bb[jt]};
#pragma unroll
        for (int kt = 0; kt < 4; kt++)
#pragma unroll
            for (int rt = 0; rt < 2; rt++)
                acc[rt][jt] = __builtin_amdgcn_mfma_f32_16x16x32_bf16(af[rt][kt], wf[jt * 4 + kt],
                                                                     acc[rt][jt], 0, 0, 0);
    }
}

// swapped store: lane holds 4 consecutive couts of one pt -> one ds_write_b64
__device__ __forceinline__ void store_relu_sw(char* __restrict__ out, f32x4 acc[2][2],
                                              int lane, int rowbase, int cout0, int asw) {
#pragma unroll
    for (int rt = 0; rt < 2; rt++) {
        int pt = rowbase + rt * 16 + (lane & 15);
#pragma unroll
        for (int jt = 0; jt < 2; jt++) {
            int c0 = cout0 + jt * 16;
            short4v v;
#pragma unroll
            for (int r = 0; r < 4; r++) v[r] = f2bf(fmaxf(acc[rt][jt][r], 0.0f));
            int byte = pt * (NC * 2) + c0 * 2;
            *(short4v*)(out + (byte ^ asw)) = v;
        }
    }
}

__global__ __launch_bounds__(512, 1) void mlp_mfma_kernel(
    const float* __restrict__ xyz1, const float* __restrict__ feat1,
    const float* __restrict__ xyz2, const float* __restrict__ feat2,
    const ushort* __restrict__ w0t, const float* __restrict__ b0,
    const ushort* __restrict__ w1t, const float* __restrict__ b1,
    const ushort* __restrict__ w2t, const float* __restrict__ b2,
    const int* __restrict__ knn, float* __restrict__ out_feat) {

    __shared__ __align__(16) char wl0[NC * CINP * 2];     // 40960
    __shared__ __align__(16) char bufIn[NPT * CINP * 2];  // 20480
    __shared__ __align__(16) char bufB[NPT * NC * 2];     // 16384
    __shared__ __align__(16) char bufC[NPT * NC * 2];     // 16384
    __shared__ __align__(16) float biasL[2][NC];          // 1024  (total 95232)

    int blk = blockIdx.x;               // 256 blocks, 1 per CU
    int b = blk >> 5;                   // 32 blocks per batch
    int qbase0 = (blk & 31) << 7;       // 128 queries per block
    int tid = threadIdx.x;
    int lane = tid & 63;
    int w = tid >> 6;                   // 0..7
    int wrow = w & 1;                   // 32-pt row half
    int wjt = w >> 1;                   // 32-cout quarter
    const size_t bn = ((size_t)b << 12);

    int rowbase = wrow * 32;
    int arow0 = rowbase + (lane & 15);
    int asw = (lane & 7) << 4;          // row&7 == lane&7 == cout&7 everywhere here
    int kseg = (lane >> 4) * 8;
    int coutw = wjt * 32 + (lane & 15);       // weight-frag row (W^T cout)
    int cout0 = wjt * 32 + (lane >> 4) * 4;   // swapped acc/store cout base (+jt*16)

    // stage L0/L1 biases (f32) into LDS; L2 bias in registers (non-swapped acc)
    if (tid < NC) biasL[0][tid] = b0[tid];
    else if (tid < 2 * NC) biasL[1][tid - NC] = b1[tid - NC];
    float bb2[2];
#pragma unroll
    for (int jt = 0; jt < 2; jt++) bb2[jt] = b2[coutw + jt * 16];

    // one-time: this wave's L1/L2 weight fragments -> registers (64 VGPR)
    short8 w1f[8], w2f[8];
#pragma unroll
    for (int jt = 0; jt < 2; jt++)
#pragma unroll
        for (int kt = 0; kt < 4; kt++) {
            int cout = coutw + jt * 16;
            w1f[jt * 4 + kt] = *(const short8*)(w1t + cout * NC + kt * 32 + kseg);
            w2f[jt * 4 + kt] = *(const short8*)(w2t + cout * NC + kt * 32 + kseg);
        }

    // stage L0 weights into LDS (swizzled)
    stage_w<CINP>(wl0, w0t, NC, tid, 512);

    Stage st;
    gather_load(st, xyz1, feat1, xyz2, feat2, knn, bn, qbase0, tid);
    gather_store(st, bufIn, tid);
    __syncthreads();

    for (int g = 0; g < NG; ++g) {
        int qb = qbase0 + g * NGQ;
        bool more = (g + 1 < NG);

        // issue next group's global gathers early (latency hides under L0/L1)
        if (more) gather_load(st, xyz1, feat1, xyz2, feat2, knn, bn, qb + NGQ, tid);

        f32x4 acc[2][2];
        // ---- P0. layer 0 (swapped): bufIn[64][160] -> bufB[64][128] ----
        layer0_sw(bufIn, wl0, biasL[0], acc, arow0, asw, kseg, coutw, cout0);
        store_relu_sw(bufB, acc, lane, rowbase, cout0, asw);
        __syncthreads();    // bar1: L0 bufIn reads + bufB writes done;
                            //       also orders prev-iter P2 bufC reads
                            //       before this P1's bufC writes

        // ---- P1. next gather -> bufIn  ||  layer 1 (swapped): bufB -> bufC ----
        if (more) gather_store(st, bufIn, tid);
        layer_rw_sw(bufB, w1f, biasL[1], acc, arow0, asw, kseg, cout0);
        store_relu_sw(bufC, acc, lane, rowbase, cout0, asw);
        __syncthreads();    // bar2: bufIn(g+1) + bufC(g) visible;
                            //       bufB reads complete before next P0 writes

        // ---- P2. layer 2 (non-swapped): bufC -> maxpool -> global ----
        // (no trailing barrier: P2 reads bufC; next P0 touches bufIn/bufB
        //  only; next bar1 orders bufC reads vs next P1 writes)
        layer_rw_ns(bufC, w2f, bb2, acc, arow0, asw, kseg);

#pragma unroll
        for (int rt = 0; rt < 2; rt++) {
            int n = qb + wrow * 2 + rt;
            float mx[2];
#pragma unroll
            for (int jt = 0; jt < 2; jt++) {
                float v = fmaxf(fmaxf(acc[rt][jt][0], acc[rt][jt][1]),
                                fmaxf(acc[rt][jt][2], acc[rt][jt][3]));
                v = fmaxf(v, 0.0f);
                v = fmaxf(v, __shfl_xor(v, 16));
                v = fmaxf(v, __shfl_xor(v, 32));
                mx[jt] = v;
            }
            if (lane < 16) {
                float* o = out_feat + (bn + n) * NC + wjt * 32 + lane;
                o[0] = mx[0];
                o[16] = mx[1];
            }
        }
    }
}

// ---------------------------------------------------------------------------
extern "C" void kernel_launch(void* const* d_in, const int* in_sizes, int n_in,
                              void* d_out, int out_size, void* d_ws, size_t ws_size,
                              hipStream_t stream) {
    const float* xyz1  = (const float*)d_in[0];
    const float* feat1 = (const float*)d_in[1];
    const float* xyz2  = (const float*)d_in[2];
    const float* feat2 = (const float*)d_in[3];
    const float* W0 = (const float*)d_in[4]; const float* b0 = (const float*)d_in[5];
    const float* W1 = (const float*)d_in[6]; const float* b1 = (const float*)d_in[7];
    const float* W2 = (const float*)d_in[8]; const float* b2 = (const float*)d_in[9];
    float* out = (float*)d_out;

    // ws layout: w0t 40960 | w1t 32768 | w2t 32768 | knn idx 2 MB |
    //            xyz2 packed 512 KB | fb_count 4 B | fb_list 128 KB
    ushort* w0t = (ushort*)d_ws;
    ushort* w1t = (ushort*)((char*)d_ws + 40960);
    ushort* w2t = (ushort*)((char*)d_ws + 73728);
    int* knn = (int*)((char*)d_ws + 106496);
    float4* x2p = (float4*)((char*)d_ws + 106496 + 2097152);
    int* fb_count = (int*)((char*)d_ws + 106496 + 2097152 + 524288);
    int* fb_list = fb_count + 1;

    hipLaunchKernelGGL(convert_w_kernel, dim3(384), dim3(160), 0, stream,
                       W0, W1, W2, w0t, w1t, w2t);

    hipLaunchKernelGGL(copy_xyz_kernel, dim3(96), dim3(256), 0, stream, xyz1, out);

    hipLaunchKernelGGL(pack_xyz2_kernel, dim3(NB * NM / 256), dim3(256), 0, stream,
                       xyz2, x2p, fb_count);

    hipLaunchKernelGGL(knn_kernel, dim3(NB * NN / 8), dim3(512), 0, stream,
                       xyz1, x2p, knn, fb_count, fb_list);

    hipLaunchKernelGGL(knn_fix_kernel, dim3(256), dim3(512), 0, stream,
                       xyz1, x2p, fb_count, fb_list, knn);

    hipLaunchKernelGGL(mlp_mfma_kernel, dim3(256), dim3(512), 0, stream,
                       xyz1, feat1, xyz2, feat2, w0t, b0, w1t, b1, w2t, b2,
                       knn, out + (size_t)NB * NN * 3);
}

// Round 17
// 212.724 us; speedup vs baseline: 1.0891x; 1.0891x over previous
//
#include <hip/hip_runtime.h>
#include <hip/hip_bf16.h>

#define NB 8
#define NN 4096
#define NM 4096
#define NC 128
#define NK 16
#define CINP 160   // cin padded for layer 0 (5 K-tiles of 32)
#define NGQ 4      // queries per group
#define NPT 64     // points per group (NGQ*16)
#define NG 32      // groups per block (128 queries / block)

typedef __attribute__((ext_vector_type(8))) short short8;
typedef __attribute__((ext_vector_type(4))) short short4v;
typedef __attribute__((ext_vector_type(4))) float f32x4;

__device__ __forceinline__ short f2bf(float f) {
    __hip_bfloat16 h = __float2bfloat16(f);
    return (short)__builtin_bit_cast(unsigned short, h);
}

// ---------------------------------------------------------------------------
// Kernel A: weight transpose + bf16 convert.  W0[131][128] -> w0t[128][160]
// ---------------------------------------------------------------------------
__global__ void convert_w_kernel(const float* __restrict__ W0, const float* __restrict__ W1,
                                 const float* __restrict__ W2, ushort* __restrict__ w0t,
                                 ushort* __restrict__ w1t, ushort* __restrict__ w2t) {
    int bx = blockIdx.x;            // 0..383
    int mat = bx >> 7;
    int cout = bx & 127;
    int k = threadIdx.x;            // 0..159
    if (mat == 0) {
        float v = (k < 131) ? W0[k * NC + cout] : 0.0f;
        w0t[cout * CINP + k] = (ushort)f2bf(v);
    } else if (k < 128) {
        const float* W = (mat == 1) ? W1 : W2;
        ushort* wt = (mat == 1) ? w1t : w2t;
        wt[cout * NC + k] = (ushort)f2bf(W[k * NC + cout]);
    }
}

// ---------------------------------------------------------------------------
// Kernel 0: copy xyz1 -> d_out; pack xyz2 -> (x,y,z,|b|^2) float4
// ---------------------------------------------------------------------------
__global__ void copy_xyz_kernel(const float* __restrict__ src, float* __restrict__ dst) {
    int i = blockIdx.x * blockDim.x + threadIdx.x;   // 24576 float4s exactly
    ((float4*)dst)[i] = ((const float4*)src)[i];
}

__global__ void pack_xyz2_kernel(const float* __restrict__ xyz2, float4* __restrict__ packed) {
    int i = blockIdx.x * blockDim.x + threadIdx.x;   // B*M total
    const float* p = xyz2 + 3 * (size_t)i;
    float x = p[0], y = p[1], z = p[2];
    packed[i] = make_float4(x, y, z, x * x + y * y + z * z);
}

// ---------------------------------------------------------------------------
// Kernel 1: KNN — R8/R17 structure (verified best; total 212.8us).
//   LDS-staged batch slice; one query per wave; keys-only merge-select
//   top-4; ordinal binary search for exact 16th-smallest; register-stash
//   Phase B; inline exact payload fallback (P~0.7%/query).
//   R18-R21 lesson: every replacement of the stash (LDS/L2 recompute,
//   deferred fallback kernel) measured net-slower end-to-end.
// ---------------------------------------------------------------------------
__device__ __forceinline__ unsigned f2ord(float f) {
    unsigned u = __builtin_bit_cast(unsigned, f);
    return (u & 0x80000000u) ? ~u : (u | 0x80000000u);
}
__device__ __forceinline__ float ord2f(unsigned u) {
    unsigned b = (u & 0x80000000u) ? (u & 0x7fffffffu) : ~u;
    return __builtin_bit_cast(float, b);
}

template<int KC>
__device__ __forceinline__ void scan_lane(const float4* __restrict__ x2p, int lane,
                                          float ax, float ay, float az,
                                          float* bd, int* bi) {
#pragma unroll
    for (int j = 0; j < KC; j++) { bd[j] = 3.4e38f; bi[j] = -1; }
#pragma unroll 2
    for (int i = 0; i < 64; i++) {
        int m = (i << 6) | lane;
        float4 f = x2p[m];
        float v = fmaf(f.x, ax, fmaf(f.y, ay, fmaf(f.z, az, f.w)));
        int vi = m;
#pragma unroll
        for (int j = 0; j < KC; j++) {
            bool c = v < bd[j];
            float nd = c ? v : bd[j];
            float cv = c ? bd[j] : v;
            int ni = c ? vi : bi[j];
            int ci = c ? bi[j] : vi;
            bd[j] = nd; bi[j] = ni; v = cv; vi = ci;
        }
    }
}

template<int KC>
__device__ __forceinline__ float extract16(float* bd, int* bi, int lane, int& outm) {
    float lastd = 0.0f;
    for (int r = 0; r < 16; r++) {
        float md = bd[0]; int mm = bi[0];
#pragma unroll
        for (int s = 1; s < 64; s <<= 1) {
            float od = __shfl_xor(md, s);
            int om = __shfl_xor(mm, s);
            bool t = (od < md) || (od == md && om < mm);
            md = t ? od : md;
            mm = t ? om : mm;
        }
        if (bd[0] == md && bi[0] == mm) {
#pragma unroll
            for (int j = 0; j < KC - 1; j++) { bd[j] = bd[j + 1]; bi[j] = bi[j + 1]; }
            bd[KC - 1] = 3.4e38f; bi[KC - 1] = -1;
        }
        if (lane == r) outm = mm;
        lastd = md;
    }
    return lastd;
}

__global__ __launch_bounds__(512, 4) void knn_kernel(const float* __restrict__ xyz1,
                                                     const float4* __restrict__ xyz2p,
                                                     int* __restrict__ out_idx) {
    __shared__ __align__(16) float4 smem[NM];   // 64 KB: batch slice of packed xyz2

    int tid = threadIdx.x;
    int lane = tid & 63;
    int w = tid >> 6;
    int Q = blockIdx.x * 8 + w;
    int b = Q >> 12;                 // all 8 waves of a block share one batch
    const float4* x2g = xyz2p + ((size_t)b << 12);

    // cooperative stage: 64 KB, 8 float4 per thread, conflict-free stride
#pragma unroll
    for (int j = 0; j < NM / 512; j++) smem[j * 512 + tid] = x2g[j * 512 + tid];

    const float* qp = xyz1 + (size_t)Q * 3;
    float ax = -2.0f * qp[0], ay = -2.0f * qp[1], az = -2.0f * qp[2];
    __syncthreads();

    // ---- Phase A: LDS reads + f32 stash + keys-only top-4 merge network ----
    float sv[64];
    float t0 = 3.4e38f, t1 = 3.4e38f, t2 = 3.4e38f, t3 = 3.4e38f;
#pragma unroll
    for (int i = 0; i < 64; i += 2) {
        float4 f = smem[(i << 6) | lane];
        float4 g = smem[((i + 1) << 6) | lane];
        float s0 = fmaf(f.x, ax, fmaf(f.y, ay, fmaf(f.z, az, f.w)));
        float s1 = fmaf(g.x, ax, fmaf(g.y, ay, fmaf(g.z, az, g.w)));
        sv[i] = s0; sv[i + 1] = s1;
        float v0 = fminf(s0, s1), v1 = fmaxf(s0, s1);
        t3 = fminf(fminf(t3, fmaxf(t2, v0)), fmaxf(t1, v1));
        t2 = fminf(fminf(t2, fmaxf(t1, v0)), fmaxf(t0, v1));
        t1 = fminf(fminf(fmaxf(t0, v0), t1), v1);
        t0 = fminf(t0, v0);
    }

    // ---- Extract exact 16th-smallest via ordinal binary search ----
    unsigned k0 = f2ord(t0), k1 = f2ord(t1), k2 = f2ord(t2), k3 = f2ord(t3);
    unsigned lo = 0u, hi = 0xffffffffu;
    for (int it = 0; it < 32; ++it) {
        unsigned mid = lo + ((hi - lo) >> 1);
        int c = __popcll(__ballot(k0 <= mid)) + __popcll(__ballot(k1 <= mid))
              + __popcll(__ballot(k2 <= mid)) + __popcll(__ballot(k3 <= mid));
        if (c >= 16) hi = mid; else lo = mid + 1;
    }
    float thr = ord2f(hi);           // exact 16th-smallest key (ties included)

    if (!__any(k3 <= hi)) {
        // ---- Phase B: register-stash scan, ordered emission, zero memory ----
        int base = 0;
#pragma unroll
        for (int i = 0; i < 64; ++i) {
            bool hit = sv[i] <= thr;
            unsigned long long mask = __ballot(hit);
            if (mask) {                    // wave-uniform skip (~70% of iters)
                int pos = base + __popcll(mask & ((1ull << lane) - 1));
                if (hit && pos < NK)
                    out_idx[(size_t)Q * NK + pos] = (i << 6) | lane;
                base += __popcll(mask);
            }
        }
    } else {
        // conservative exactness fallback (P ~ 0.7%/query): payload depth-16
        float bd[16]; int bi[16];
        scan_lane<16>(smem, lane, ax, ay, az, bd, bi);
        int outm = -1;
        extract16<16>(bd, bi, lane, outm);
        if (lane < NK) out_idx[(size_t)Q * NK + lane] = outm;
    }
}

// ---------------------------------------------------------------------------
// Kernel 2: fused gather + corr + 3-layer MLP (bf16 MFMA) + maxpool.
// R17-verified best: hybrid orientation — swapped L0/L1 (b64 LDS stores),
// non-swapped L2 (cheap maxpool) — 2 barriers per iteration.
// ---------------------------------------------------------------------------
struct Stage {
    float4 r[8];          // r[0..3] = feat2 slice, r[4..7] = feat1 slice
    float dx, dy, dz;     // xyz diff (tid < NPT only)
};

__device__ __forceinline__ void gather_load(Stage& st,
    const float* __restrict__ xyz1, const float* __restrict__ feat1,
    const float* __restrict__ xyz2, const float* __restrict__ feat2,
    const int* __restrict__ knn, size_t bn, int qbase, int tid) {
    int pt = tid >> 3, oct = tid & 7;              // pt 0..63 with 512 threads
    int n = qbase + (pt >> 4);
    int m = knn[(bn + n) * NK + (pt & 15)];
    const float* f2 = feat2 + (bn + m) * NC + oct * 16;
    const float* f1 = feat1 + (bn + n) * NC + oct * 16;
#pragma unroll
    for (int i = 0; i < 4; i++) st.r[i] = ((const float4*)f2)[i];
#pragma unroll
    for (int i = 0; i < 4; i++) st.r[4 + i] = ((const float4*)f1)[i];
    if (tid < NPT) {
        int pt2 = tid;
        int n2 = qbase + (pt2 >> 4);
        int m2 = knn[(bn + n2) * NK + (pt2 & 15)];
        const float* p2 = xyz2 + (bn + m2) * 3;
        const float* p1 = xyz1 + (bn + n2) * 3;
        st.dx = p2[0] - p1[0];
        st.dy = p2[1] - p1[1];
        st.dz = p2[2] - p1[2];
    }
}

__device__ __forceinline__ void gather_store(const Stage& st, char* __restrict__ buf, int tid) {
    int pt = tid >> 3, oct = tid & 7;
    short8 c0, c1;
    c0[0] = f2bf(st.r[0].x * st.r[4].x); c0[1] = f2bf(st.r[0].y * st.r[4].y);
    c0[2] = f2bf(st.r[0].z * st.r[4].z); c0[3] = f2bf(st.r[0].w * st.r[4].w);
    c0[4] = f2bf(st.r[1].x * st.r[5].x); c0[5] = f2bf(st.r[1].y * st.r[5].y);
    c0[6] = f2bf(st.r[1].z * st.r[5].z); c0[7] = f2bf(st.r[1].w * st.r[5].w);
    c1[0] = f2bf(st.r[2].x * st.r[6].x); c1[1] = f2bf(st.r[2].y * st.r[6].y);
    c1[2] = f2bf(st.r[2].z * st.r[6].z); c1[3] = f2bf(st.r[2].w * st.r[6].w);
    c1[4] = f2bf(st.r[3].x * st.r[7].x); c1[5] = f2bf(st.r[3].y * st.r[7].y);
    c1[6] = f2bf(st.r[3].z * st.r[7].z); c1[7] = f2bf(st.r[3].w * st.r[7].w);
    int base = pt * (CINP * 2) + oct * 32;
    int sw = (pt & 7) << 4;
    *(short8*)(buf + (base ^ sw)) = c0;
    *(short8*)(buf + ((base + 16) ^ sw)) = c1;
    if (tid < NPT) {
        int pt2 = tid;
        short8 cz = {0, 0, 0, 0, 0, 0, 0, 0};
        short8 cx = cz;
        cx[0] = f2bf(st.dx); cx[1] = f2bf(st.dy); cx[2] = f2bf(st.dz);
        int base2 = pt2 * (CINP * 2) + 256;
        int sw2 = (pt2 & 7) << 4;
        *(short8*)(buf + (base2 ^ sw2)) = cx;
        *(short8*)(buf + ((base2 + 16) ^ sw2)) = cz;
        *(short8*)(buf + ((base2 + 32) ^ sw2)) = cz;
        *(short8*)(buf + ((base2 + 48) ^ sw2)) = cz;
    }
}

// stage a [rows][COLS] bf16 weight matrix into LDS with the row-XOR swizzle
template<int COLS>
__device__ __forceinline__ void stage_w(char* __restrict__ dst, const ushort* __restrict__ src,
                                        int rows, int tid, int nthreads) {
    const int CPR = COLS / 8;            // short8 chunks per row
    int chunks = rows * CPR;
    for (int c = tid; c < chunks; c += nthreads) {
        int row = c / CPR;
        int col8 = c % CPR;
        short8 v = *(const short8*)(src + c * 8);
        int byte = row * (COLS * 2) + col8 * 16;
        *(short8*)(dst + (byte ^ ((row & 7) << 4))) = v;
    }
}

// L0 (swapped operands): LDS weights as A, activations as B.  [verified R11/R13]
__device__ __forceinline__ void layer0_sw(const char* __restrict__ in, const char* __restrict__ wl,
                                          const float* __restrict__ bl, f32x4 acc[2][2],
                                          int arow0, int asw, int kseg, int coutw, int cout0) {
    short8 af[2][5];
#pragma unroll
    for (int rt = 0; rt < 2; rt++)
#pragma unroll
        for (int kt = 0; kt < 5; kt++) {
            int byte = (arow0 + rt * 16) * (CINP * 2) + (kt * 32 + kseg) * 2;
            af[rt][kt] = *(const short8*)(in + (byte ^ asw));
        }
#pragma unroll
    for (int jt = 0; jt < 2; jt++) {
        float4 bb = *(const float4*)(bl + cout0 + jt * 16);
#pragma unroll
        for (int rt = 0; rt < 2; rt++)
            acc[rt][jt] = (f32x4){bb.x, bb.y, bb.z, bb.w};
        int wbase = (coutw + jt * 16) * (CINP * 2) + kseg * 2;
#pragma unroll
        for (int kt = 0; kt < 5; kt++) {
            short8 wf = *(const short8*)(wl + ((wbase + kt * 64) ^ asw));
#pragma unroll
            for (int rt = 0; rt < 2; rt++)
                acc[rt][jt] = __builtin_amdgcn_mfma_f32_16x16x32_bf16(wf, af[rt][kt],
                                                                     acc[rt][jt], 0, 0, 0);
        }
    }
}

// L1 (swapped): register weight frags as A (wf[jt*4+kt], const-indexed)
__device__ __forceinline__ void layer_rw_sw(const char* __restrict__ in, const short8* __restrict__ wf,
                                            const float* __restrict__ bl, f32x4 acc[2][2],
                                            int arow0, int asw, int kseg, int cout0) {
    short8 af[2][4];
#pragma unroll
    for (int rt = 0; rt < 2; rt++)
#pragma unroll
        for (int kt = 0; kt < 4; kt++) {
            int byte = (arow0 + rt * 16) * (NC * 2) + (kt * 32 + kseg) * 2;
            af[rt][kt] = *(const short8*)(in + (byte ^ asw));
        }
#pragma unroll
    for (int jt = 0; jt < 2; jt++) {
        float4 bb = *(const float4*)(bl + cout0 + jt * 16);
#pragma unroll
        for (int rt = 0; rt < 2; rt++)
            acc[rt][jt] = (f32x4){bb.x, bb.y, bb.z, bb.w};
#pragma unroll
        for (int kt = 0; kt < 4; kt++)
#pragma unroll
            for (int rt = 0; rt < 2; rt++)
                acc[rt][jt] = __builtin_amdgcn_mfma_f32_16x16x32_bf16(wf[jt * 4 + kt], af[rt][kt],
                                                                     acc[rt][jt], 0, 0, 0);
    }
}

// L2 (NON-swapped, R10-verified): activations as A, register weight frags as B.
// acc holds [cout = lane&15 col][pt = (lane>>4)*4+r row] -> maxpool-friendly.
__device__ __forceinline__ void layer_rw_ns(const char* __restrict__ in, const short8* __restrict__ wf,
                                            const float bb[2], f32x4 acc[2][2],
                                            int arow0, int asw, int kseg) {
    short8 af[2][4];
#pragma unroll
    for (int rt = 0; rt < 2; rt++)
#pragma unroll
        for (int kt = 0; kt < 4; kt++) {
            int byte = (arow0 + rt * 16) * (NC * 2) + (kt * 32 + kseg) * 2;
            af[rt][kt] = *(const short8*)(in + (byte ^ asw));
        }
#pragma unroll
    for (int jt = 0; jt < 2; jt++) {
#pragma unroll
        for (int rt = 0; rt < 2; rt++)
            acc[rt][jt] = (f32x4){bb[jt], bb[jt], bb[jt], bb[jt]};
#pragma unroll
        for (int kt = 0; kt < 4; kt++)
#pragma unroll
            for (int rt = 0; rt < 2; rt++)
                acc[rt][jt] = __builtin_amdgcn_mfma_f32_16x16x32_bf16(af[rt][kt], wf[jt * 4 + kt],
                                                                     acc[rt][jt], 0, 0, 0);
    }
}

// swapped store: lane holds 4 consecutive couts of one pt -> one ds_write_b64
__device__ __forceinline__ void store_relu_sw(char* __restrict__ out, f32x4 acc[2][2],
                                              int lane, int rowbase, int cout0, int asw) {
#pragma unroll
    for (int rt = 0; rt < 2; rt++) {
        int pt = rowbase + rt * 16 + (lane & 15);
#pragma unroll
        for (int jt = 0; jt < 2; jt++) {
            int c0 = cout0 + jt * 16;
            short4v v;
#pragma unroll
            for (int r = 0; r < 4; r++) v[r] = f2bf(fmaxf(acc[rt][jt][r], 0.0f));
            int byte = pt * (NC * 2) + c0 * 2;
            *(short4v*)(out + (byte ^ asw)) = v;
        }
    }
}

__global__ __launch_bounds__(512, 1) void mlp_mfma_kernel(
    const float* __restrict__ xyz1, const float* __restrict__ feat1,
    const float* __restrict__ xyz2, const float* __restrict__ feat2,
    const ushort* __restrict__ w0t, const float* __restrict__ b0,
    const ushort* __restrict__ w1t, const float* __restrict__ b1,
    const ushort* __restrict__ w2t, const float* __restrict__ b2,
    const int* __restrict__ knn, float* __restrict__ out_feat) {

    __shared__ __align__(16) char wl0[NC * CINP * 2];     // 40960
    __shared__ __align__(16) char bufIn[NPT * CINP * 2];  // 20480
    __shared__ __align__(16) char bufB[NPT * NC * 2];     // 16384
    __shared__ __align__(16) char bufC[NPT * NC * 2];     // 16384
    __shared__ __align__(16) float biasL[2][NC];          // 1024  (total 95232)

    int blk = blockIdx.x;               // 256 blocks, 1 per CU
    int b = blk >> 5;                   // 32 blocks per batch
    int qbase0 = (blk & 31) << 7;       // 128 queries per block
    int tid = threadIdx.x;
    int lane = tid & 63;
    int w = tid >> 6;                   // 0..7
    int wrow = w & 1;                   // 32-pt row half
    int wjt = w >> 1;                   // 32-cout quarter
    const size_t bn = ((size_t)b << 12);

    int rowbase = wrow * 32;
    int arow0 = rowbase + (lane & 15);
    int asw = (lane & 7) << 4;          // row&7 == lane&7 == cout&7 everywhere here
    int kseg = (lane >> 4) * 8;
    int coutw = wjt * 32 + (lane & 15);       // weight-frag row (W^T cout)
    int cout0 = wjt * 32 + (lane >> 4) * 4;   // swapped acc/store cout base (+jt*16)

    // stage L0/L1 biases (f32) into LDS; L2 bias in registers (non-swapped acc)
    if (tid < NC) biasL[0][tid] = b0[tid];
    else if (tid < 2 * NC) biasL[1][tid - NC] = b1[tid - NC];
    float bb2[2];
#pragma unroll
    for (int jt = 0; jt < 2; jt++) bb2[jt] = b2[coutw + jt * 16];

    // one-time: this wave's L1/L2 weight fragments -> registers (64 VGPR)
    short8 w1f[8], w2f[8];
#pragma unroll
    for (int jt = 0; jt < 2; jt++)
#pragma unroll
        for (int kt = 0; kt < 4; kt++) {
            int cout = coutw + jt * 16;
            w1f[jt * 4 + kt] = *(const short8*)(w1t + cout * NC + kt * 32 + kseg);
            w2f[jt * 4 + kt] = *(const short8*)(w2t + cout * NC + kt * 32 + kseg);
        }

    // stage L0 weights into LDS (swizzled)
    stage_w<CINP>(wl0, w0t, NC, tid, 512);

    Stage st;
    gather_load(st, xyz1, feat1, xyz2, feat2, knn, bn, qbase0, tid);
    gather_store(st, bufIn, tid);
    __syncthreads();

    for (int g = 0; g < NG; ++g) {
        int qb = qbase0 + g * NGQ;
        bool more = (g + 1 < NG);

        // issue next group's global gathers early (latency hides under L0/L1)
        if (more) gather_load(st, xyz1, feat1, xyz2, feat2, knn, bn, qb + NGQ, tid);

        f32x4 acc[2][2];
        // ---- P0. layer 0 (swapped): bufIn[64][160] -> bufB[64][128] ----
        layer0_sw(bufIn, wl0, biasL[0], acc, arow0, asw, kseg, coutw, cout0);
        store_relu_sw(bufB, acc, lane, rowbase, cout0, asw);
        __syncthreads();    // bar1: L0 bufIn reads + bufB writes done;
                            //       also orders prev-iter P2 bufC reads
                            //       before this P1's bufC writes

        // ---- P1. next gather -> bufIn  ||  layer 1 (swapped): bufB -> bufC ----
        if (more) gather_store(st, bufIn, tid);
        layer_rw_sw(bufB, w1f, biasL[1], acc, arow0, asw, kseg, cout0);
        store_relu_sw(bufC, acc, lane, rowbase, cout0, asw);
        __syncthreads();    // bar2: bufIn(g+1) + bufC(g) visible;
                            //       bufB reads complete before next P0 writes

        // ---- P2. layer 2 (non-swapped): bufC -> maxpool -> global ----
        // (no trailing barrier: P2 reads bufC; next P0 touches bufIn/bufB
        //  only; next bar1 orders bufC reads vs next P1 writes)
        layer_rw_ns(bufC, w2f, bb2, acc, arow0, asw, kseg);

#pragma unroll
        for (int rt = 0; rt < 2; rt++) {
            int n = qb + wrow * 2 + rt;
            float mx[2];
#pragma unroll
            for (int jt = 0; jt < 2; jt++) {
                float v = fmaxf(fmaxf(acc[rt][jt][0], acc[rt][jt][1]),
                                fmaxf(acc[rt][jt][2], acc[rt][jt][3]));
                v = fmaxf(v, 0.0f);
                v = fmaxf(v, __shfl_xor(v, 16));
                v = fmaxf(v, __shfl_xor(v, 32));
                mx[jt] = v;
            }
            if (lane < 16) {
                float* o = out_feat + (bn + n) * NC + wjt * 32 + lane;
                o[0] = mx[0];
                o[16] = mx[1];
            }
        }
    }
}

// ---------------------------------------------------------------------------
extern "C" void kernel_launch(void* const* d_in, const int* in_sizes, int n_in,
                              void* d_out, int out_size, void* d_ws, size_t ws_size,
                              hipStream_t stream) {
    const float* xyz1  = (const float*)d_in[0];
    const float* feat1 = (const float*)d_in[1];
    const float* xyz2  = (const float*)d_in[2];
    const float* feat2 = (const float*)d_in[3];
    const float* W0 = (const float*)d_in[4]; const float* b0 = (const float*)d_in[5];
    const float* W1 = (const float*)d_in[6]; const float* b1 = (const float*)d_in[7];
    const float* W2 = (const float*)d_in[8]; const float* b2 = (const float*)d_in[9];
    float* out = (float*)d_out;

    // ws layout: w0t 40960 | w1t 32768 | w2t 32768 | knn idx 2 MB | xyz2 packed 512 KB
    ushort* w0t = (ushort*)d_ws;
    ushort* w1t = (ushort*)((char*)d_ws + 40960);
    ushort* w2t = (ushort*)((char*)d_ws + 73728);
    int* knn = (int*)((char*)d_ws + 106496);
    float4* x2p = (float4*)((char*)d_ws + 106496 + 2097152);

    hipLaunchKernelGGL(convert_w_kernel, dim3(384), dim3(160), 0, stream,
                       W0, W1, W2, w0t, w1t, w2t);

    hipLaunchKernelGGL(copy_xyz_kernel, dim3(96), dim3(256), 0, stream, xyz1, out);

    hipLaunchKernelGGL(pack_xyz2_kernel, dim3(NB * NM / 256), dim3(256), 0, stream,
                       xyz2, x2p);

    hipLaunchKernelGGL(knn_kernel, dim3(NB * NN / 8), dim3(512), 0, stream,
                       xyz1, x2p, knn);

    hipLaunchKernelGGL(mlp_mfma_kernel, dim3(256), dim3(512), 0, stream,
                       xyz1, feat1, xyz2, feat2, w0t, b0, w1t, b1, w2t, b2,
                       knn, out + (size_t)NB * NN * 3);
}